// Round 14
// baseline (732.613 us; speedup 1.0000x reference)
//
#include <hip/hip_runtime.h>

// ---------------------------------------------------------------------------
// VGAE encoder, MI355X. Two adj (16384^2 f32, 1 GiB) GEMMs dominate.
// Split-bf16 (hi+lo, 3 MFMA terms) for fp32 accuracy on the bf16 matrix core.
// R1-R13: adj pass ~345us (~3.1 TB/s) invariant to burst size, depth, order,
// occupancy, M, pattern (linear==tiled), staging primitive, B traffic.
// Surviving theory: all streams share each wave's in-order vmcnt queue and
// every macro drains it -> adj queue empty much of each macro (Little's law
// needs >=21KB/CU outstanding CONTINUOUSLY). R7's role-split test was
// invalidated by ~250-VGPR union spill.
// R14: lean producer/consumer. 768 thr = 12 waves: 0-3 producers (pure adj
// queue; 16 rows x 1KB/macro; ~90 VGPR), 4-11 consumers (pure B queue +
// MFMA, one 32x32 tile each; ~100 VGPR). Double-buffered 128KB LDS, ONE
// barrier/macro. Producers keep ~64KB/CU adj loads in flight continuously.
// ---------------------------------------------------------------------------

typedef __bf16 bf16_t;
typedef __attribute__((ext_vector_type(4))) __bf16 bf16x4;
typedef __attribute__((ext_vector_type(8))) __bf16 bf16x8;
typedef __attribute__((ext_vector_type(16))) float f32x16;
typedef __attribute__((ext_vector_type(4)))  float f32x4;

#define N_NODES 16384
#define MFMA3(ACC, A, B) \
    ACC = __builtin_amdgcn_mfma_f32_32x32x16_bf16(A, B, ACC, 0, 0, 0)

// Fragment layout for the B operand of mfma_f32_32x32x16_bf16:
// element (k=r, col=c) -> 1KiB units indexed by (K16 = r>>4, cblk = c>>5),
// within a unit: lane = (c&31) + 32*((r>>3)&1) holds 8 bf16 (k = ..8g..8g+7).
__device__ __forceinline__ int frag_off(int r, int c) {
    int K16  = r >> 4;
    int cblk = c >> 5;
    int g    = (r >> 3) & 1;
    int lane = (c & 31) + (g << 5);
    return ((K16 * 4 + cblk) << 9) + (lane << 3) + (r & 7);
}

__device__ __forceinline__ float4 relu_add4(float4 a, float4 b) {
    float4 r;
    r.x = fmaxf(a.x + b.x, 0.f); r.y = fmaxf(a.y + b.y, 0.f);
    r.z = fmaxf(a.z + b.z, 0.f); r.w = fmaxf(a.w + b.w, 0.f);
    return r;
}

// ---------------------------------------------------------------------------
// Small fp32 GEMM producer: out = A[16384][K] @ W[K][128]; epilogue splits
// each output into bf16 hi/lo and scatters into the fragment layout.
// ADD2: A := relu(A + A2) elementwise (fused partial-reduce of the hidden).
// ---------------------------------------------------------------------------
template<int K, bool FUSED, bool ADD2>
__global__ __launch_bounds__(256)
void producer_kernel(const float* __restrict__ A,
                     const float* __restrict__ A2,
                     const float* __restrict__ W,
                     const float* __restrict__ Wa,
                     const float* __restrict__ Wb,
                     bf16_t* __restrict__ Bh,
                     bf16_t* __restrict__ Bl)
{
    __shared__ float As[32][128];   // k-major A tile: As[k][r]
    __shared__ float Wsh[32][128];  // Wsh[k][c]
    const int t    = threadIdx.x;
    const int row0 = blockIdx.x * 128;
    const int tc   = t & 15, tr = t >> 4;   // 16x16 thread grid, 8x8 outs each

    float acc[8][8];
    #pragma unroll
    for (int i = 0; i < 8; ++i)
        #pragma unroll
        for (int j = 0; j < 8; ++j) acc[i][j] = 0.f;

    const int ra = t >> 1, ks = (t & 1) << 4;   // A staging: 16 f32/thread
    const int wk = t >> 3, wc = (t & 7) << 4;   // W staging: 16 f32/thread

    for (int k0 = 0; k0 < K; k0 += 32) {
        const float* ap = A + (size_t)(row0 + ra) * K + k0 + ks;
        float4 a0 = *(const float4*)(ap);
        float4 a1 = *(const float4*)(ap + 4);
        float4 a2 = *(const float4*)(ap + 8);
        float4 a3 = *(const float4*)(ap + 12);
        if (ADD2) {
            const float* ap2 = A2 + (size_t)(row0 + ra) * K + k0 + ks;
            a0 = relu_add4(a0, *(const float4*)(ap2));
            a1 = relu_add4(a1, *(const float4*)(ap2 + 4));
            a2 = relu_add4(a2, *(const float4*)(ap2 + 8));
            a3 = relu_add4(a3, *(const float4*)(ap2 + 12));
        }
        float4 w0, w1, w2, w3;
        if (!FUSED) {
            const float* wp = W + (size_t)(k0 + wk) * 128 + wc;
            w0 = *(const float4*)(wp);     w1 = *(const float4*)(wp + 4);
            w2 = *(const float4*)(wp + 8); w3 = *(const float4*)(wp + 12);
        } else {
            const float* wp = (wc < 64) ? (Wa + (size_t)(k0 + wk) * 64 + wc)
                                        : (Wb + (size_t)(k0 + wk) * 64 + (wc - 64));
            w0 = *(const float4*)(wp);     w1 = *(const float4*)(wp + 4);
            w2 = *(const float4*)(wp + 8); w3 = *(const float4*)(wp + 12);
        }
        __syncthreads();   // previous iteration's compute done before overwrite
        {
            float tmp[16] = {a0.x,a0.y,a0.z,a0.w, a1.x,a1.y,a1.z,a1.w,
                             a2.x,a2.y,a2.z,a2.w, a3.x,a3.y,a3.z,a3.w};
            #pragma unroll
            for (int j = 0; j < 16; ++j) As[ks + j][ra] = tmp[j];
            *(float4*)&Wsh[wk][wc     ] = w0;
            *(float4*)&Wsh[wk][wc +  4] = w1;
            *(float4*)&Wsh[wk][wc +  8] = w2;
            *(float4*)&Wsh[wk][wc + 12] = w3;
        }
        __syncthreads();
        #pragma unroll 4
        for (int k = 0; k < 32; ++k) {
            float av[8], wv[8];
            *(float4*)&av[0] = *(const float4*)&As[k][8 * tr];
            *(float4*)&av[4] = *(const float4*)&As[k][8 * tr + 4];
            *(float4*)&wv[0] = *(const float4*)&Wsh[k][8 * tc];
            *(float4*)&wv[4] = *(const float4*)&Wsh[k][8 * tc + 4];
            #pragma unroll
            for (int i = 0; i < 8; ++i)
                #pragma unroll
                for (int j = 0; j < 8; ++j)
                    acc[i][j] = fmaf(av[i], wv[j], acc[i][j]);
        }
    }

    #pragma unroll
    for (int i = 0; i < 8; ++i) {
        int r = row0 + 8 * tr + i;
        #pragma unroll
        for (int j = 0; j < 8; ++j) {
            int c = 8 * tc + j;
            float v = acc[i][j];
            bf16_t h = (bf16_t)v;
            bf16_t l = (bf16_t)(v - (float)h);
            int off = frag_off(r, c);
            Bh[off] = h;
            Bl[off] = l;
        }
    }
}

// ---------------------------------------------------------------------------
// Big kernel: P_kh = adj[rows, kh-half] @ B[kh-half], M-tile 64, K-half 8192.
// grid 512 (256 mt x 2 kh), 768 thr = 12 waves, 1 block/CU (128KB LDS):
//   waves 0-3  PRODUCERS: wave pw stages rows pw*16..+15 per macro, one 1KB
//     dwordx4 burst per row; cvt f32->bf16 hi/lo; swizzled LDS write. Their
//     vmcnt queue holds ONLY adj loads, issued a full macro ahead and kept
//     in flight across the barrier (~16KB/wave continuous).
//   waves 4-11 CONSUMERS: one 32x32 output tile each (2 row-half x 4 col-
//     quadrant); B frags L2->reg (2 BSets, pure-B queue) + MFMA from LDS.
// 32 macros of K=256, double-buffered LDS [2][64][256] hi+lo = 128 KB,
// ONE lgkm-only barrier per macro (p/c swap). Numerics identical to R13.
// LDS swizzle: elem (r,k) at (r<<8) + (((k>>4) ^ (r&15))<<4) + (k&15).
// ---------------------------------------------------------------------------
struct BSet { bf16x8 h[4]; bf16x8 l[4]; };   // 32 VGPRs

__global__ __launch_bounds__(768, 3)
void adj_gemm_kernel(const float* __restrict__ adj,
                     const bf16_t* __restrict__ Bh,
                     const bf16_t* __restrict__ Bl,
                     float* __restrict__ P0,
                     float* __restrict__ P1)
{
    __shared__ __align__(16) bf16_t AsH[2][64 * 256];   // 64KB
    __shared__ __align__(16) bf16_t AsL[2][64 * 256];   // 64KB
    const int t    = threadIdx.x;
    const int lane = t & 63;
    const int w    = t >> 6;                 // 0..11
    const int mt   = blockIdx.x >> 1;
    const int kh   = blockIdx.x & 1;
    const int row0 = mt << 6;
    const int hi32 = lane >> 5;
    float* const outP = kh ? P1 : P0;

    // lgkm-only barrier: ds ops drained; register-dest global loads stay in
    // flight across the barrier (counted vmcnt by compiler).
#define SYNC_LDS() do { asm volatile("s_waitcnt lgkmcnt(0)" ::: "memory"); \
                        __builtin_amdgcn_s_barrier(); } while (0)

    if (w < 4) {
        // ------------------------- PRODUCER -------------------------
        // wave w stages rows w*16+j (j=0..15), 1KB burst per row per macro.
        const float* aBase = adj + (size_t)(row0 + (w << 4)) * 16384
                                 + (kh << 13) + (lane << 2);
        int wIdx[16];
        #pragma unroll
        for (int j = 0; j < 16; ++j) {
            int row = (w << 4) + j;
            wIdx[j] = (row << 8) + ((((lane >> 2) ^ (row & 15)) << 4)
                                    + ((lane & 3) << 2));
        }
        f32x4 ar[16];

        auto loadAdj = [&](int mac) {
            const float* p = aBase + (mac << 8);
            #pragma unroll
            for (int j = 0; j < 16; ++j)
                ar[j] = __builtin_nontemporal_load(
                            (const f32x4*)(p + (size_t)j * 16384));
        };
        auto cvtWrite = [&](int buf) {
            bf16_t* const H = &AsH[buf][0];
            bf16_t* const L = &AsL[buf][0];
            #pragma unroll
            for (int j = 0; j < 16; ++j) {
                bf16x4 hv, lv;
                #pragma unroll
                for (int e = 0; e < 4; ++e) {
                    float v = ar[j][e];
                    bf16_t h = (bf16_t)v;
                    hv[e] = h;
                    lv[e] = (bf16_t)(v - (float)h);
                }
                *(bf16x4*)&H[wIdx[j]] = hv;
                *(bf16x4*)&L[wIdx[j]] = lv;
            }
        };

        loadAdj(0);
        cvtWrite(0);             // waits own adj(0) loads only
        loadAdj(1);              // adj(1) in flight across the barrier
        SYNC_LDS();              // buf0 visible
        for (int m = 0; m < 32; ++m) {
            if (m < 31) cvtWrite((m + 1) & 1);   // waits adj(m+1): 1-macro lead
            if (m < 30) loadAdj(m + 2);          // keep queue full
            SYNC_LDS();
        }
    } else {
        // ------------------------- CONSUMER -------------------------
        const int cw = w - 4;
        const int rh = cw >> 2, cq = cw & 3;     // row-half, col-quadrant
        const int frow  = (rh << 5) + (lane & 31);
        const int rbase = (frow << 8) + (hi32 << 3);
        const int rx    = frow & 15;
        const int tb    = (cq << 9) + (lane << 3);
        const int sub0  = kh << 7;               // kh*128 subs

        f32x16 acc;
        #pragma unroll
        for (int i = 0; i < 16; ++i) acc[i] = 0.f;

        BSet E, O;

        auto loadB = [&](BSet& S, int sub) {
            const size_t base = ((size_t)sub << 13) + tb;
            #pragma unroll
            for (int s = 0; s < 4; ++s) {
                S.h[s] = *(const bf16x8*)(Bh + base + (s << 11));
                S.l[s] = *(const bf16x8*)(Bl + base + (s << 11));
            }
        };
        auto computeS = [&](int buf, const BSet& S, int s) {
            const bf16_t* const H = &AsH[buf][0];
            const bf16_t* const L = &AsL[buf][0];
            #pragma unroll
            for (int k16 = 0; k16 < 4; ++k16) {
                const int u  = (s << 2) + k16;
                const int id = rbase + ((u ^ rx) << 4);
                bf16x8 ah = *(const bf16x8*)&H[id];
                bf16x8 al = *(const bf16x8*)&L[id];
                MFMA3(acc, ah, S.h[k16]);
                MFMA3(acc, ah, S.l[k16]);
                MFMA3(acc, al, S.h[k16]);
            }
        };

        loadB(E, sub0);          // warm first subs while producers stage
        loadB(O, sub0 + 1);
        SYNC_LDS();              // buf0 ready
        for (int m = 0; m < 32; ++m) {
            const int buf = m & 1;
            const int sb  = sub0 + (m << 2);
            computeS(buf, E, 0);
            loadB(E, sb + 2);
            computeS(buf, O, 1);
            loadB(O, sb + 3);
            computeS(buf, E, 2);
            if (m < 31) loadB(E, sb + 4);
            computeS(buf, O, 3);
            if (m < 31) loadB(O, sb + 5);
            SYNC_LDS();
        }

        // C write: col = cq*32 + lane&31, row map of 32x32 tile
        const int col = (cq << 5) + (lane & 31);
        const int rb  = row0 + (rh << 5) + (hi32 << 2);
        #pragma unroll
        for (int q = 0; q < 16; ++q) {
            int r = rb + (q & 3) + ((q >> 2) << 3);
            outP[(size_t)r * 128 + col] = acc[q];
        }
    }
#undef SYNC_LDS
}

// ---------------------------------------------------------------------------
// Final: T = T0+T1 ([16384][128], Z cols 0-63 | logstd cols 64-127);
// mean = Z@Wp + bp; out = noise*exp(min(logstd,10)) + mean
// ---------------------------------------------------------------------------
__global__ __launch_bounds__(256)
void final_kernel(const float* __restrict__ T0,
                  const float* __restrict__ T1,
                  const float* __restrict__ Wp,
                  const float* __restrict__ bp,
                  const float* __restrict__ noise,
                  float* __restrict__ out)
{
    __shared__ float Wps[64][64];
    __shared__ float Ts[64][64];
    const int t = threadIdx.x;
    const int row0 = blockIdx.x * 64;
    {
        int k = t >> 2, c0 = (t & 3) << 4;
        #pragma unroll
        for (int i = 0; i < 4; ++i)
            *(float4*)&Wps[k][c0 + 4 * i] = *(const float4*)&Wp[(size_t)k * 64 + c0 + 4 * i];
        #pragma unroll
        for (int i = 0; i < 4; ++i) {
            float4 z0 = *(const float4*)&T0[(size_t)(row0 + k) * 128 + c0 + 4 * i];
            float4 z1 = *(const float4*)&T1[(size_t)(row0 + k) * 128 + c0 + 4 * i];
            float4 zs; zs.x = z0.x + z1.x; zs.y = z0.y + z1.y;
            zs.z = z0.z + z1.z; zs.w = z0.w + z1.w;
            *(float4*)&Ts[k][c0 + 4 * i] = zs;
        }
    }
    __syncthreads();

    const int r  = t >> 2;
    const int c0 = (t & 3) << 4;
    float acc[16];
    #pragma unroll
    for (int j = 0; j < 16; ++j) acc[j] = bp[c0 + j];
    for (int k = 0; k < 64; ++k) {
        float a = Ts[r][k];
        #pragma unroll
        for (int j = 0; j < 16; ++j) acc[j] = fmaf(a, Wps[k][c0 + j], acc[j]);
    }
    const int grow = row0 + r;
    #pragma unroll
    for (int j = 0; j < 16; ++j) {
        size_t li = (size_t)grow * 128 + 64 + c0 + j;
        float ls = T0[li] + T1[li];
        ls = fminf(ls, 10.0f);
        out[(size_t)grow * 64 + c0 + j] =
            noise[(size_t)grow * 64 + c0 + j] * __expf(ls) + acc[j];
    }
}

// ---------------------------------------------------------------------------
extern "C" void kernel_launch(void* const* d_in, const int* in_sizes, int n_in,
                              void* d_out, int out_size, void* d_ws, size_t ws_size,
                              hipStream_t stream) {
    const float* X     = (const float*)d_in[0];
    const float* adj   = (const float*)d_in[1];
    const float* W1    = (const float*)d_in[2];
    const float* Wm    = (const float*)d_in[3];
    const float* Wsv   = (const float*)d_in[4];
    const float* Wp    = (const float*)d_in[5];
    const float* bp    = (const float*)d_in[6];
    const float* noise = (const float*)d_in[7];
    float* out = (float*)d_out;

    char* ws = (char*)d_ws;
    bf16_t* Bh = (bf16_t*)ws;                     // 4 MB
    bf16_t* Bl = (bf16_t*)(ws + (4u << 20));      // 4 MB
    float*  P0 = (float*)(ws + (8u << 20));       // 8 MB partial (kh=0)
    float*  P1 = (float*)(ws + (16u << 20));      // 8 MB partial (kh=1)

    // S1: B1 = fragsplit((X @ W1)^T)
    producer_kernel<256, false, false><<<128, 256, 0, stream>>>(
        X, nullptr, W1, nullptr, nullptr, Bh, Bl);
    // S2: hidden partials: P_kh = adj[:, kh-half] @ B1[kh-half]
    adj_gemm_kernel<<<512, 768, 0, stream>>>(adj, Bh, Bl, P0, P1);
    // S3: B2 = fragsplit((relu(P0+P1) @ [Wm|Ws])^T)   (reduce+relu fused)
    producer_kernel<128, true, true><<<128, 256, 0, stream>>>(
        P0, P1, nullptr, Wm, Wsv, Bh, Bl);
    // S4: T partials
    adj_gemm_kernel<<<512, 768, 0, stream>>>(adj, Bh, Bl, P0, P1);
    // S5: epilogue (T = P0+P1 summed on the fly)
    final_kernel<<<256, 256, 0, stream>>>(P0, P1, Wp, bp, noise, out);
}

// Round 15
// 716.942 us; speedup vs baseline: 1.0219x; 1.0219x over previous
//
#include <hip/hip_runtime.h>

// ---------------------------------------------------------------------------
// VGAE encoder, MI355X. Two adj (16384^2 f32, 1 GiB) GEMMs dominate.
// Split-bf16 (hi+lo, 3 MFMA terms) for fp32 accuracy on the bf16 matrix core.
// R1-R14: adj pass ~345us (~3.1 TB/s) invariant to EVERY within-block axis:
// burst size, prefetch depth, issue order, occupancy, M, pattern
// (linear==tiled), staging primitive (gload_lds), B traffic, wave roles.
// Last mechanism standing: CROSS-BLOCK ADDRESS CORRELATION -- all blocks
// march through K in lockstep, so at any instant the whole chip reads the
// same 1-KB k-window (same low address bits -> same few HBM channels/banks),
// then steps together. No within-block change could touch this.
// R15: per-block K-phase rotation on the best config (R9, 714us). Block
// processes macros in order (m+ph)&31, ph = (bid*5+bid/8)&31 -- valid since
// GEMM sums over K commutatively. Blocks now cover all 32 k-windows at every
// instant -> all channels active. ~4 lines changed from R9.
// ---------------------------------------------------------------------------

typedef __bf16 bf16_t;
typedef __attribute__((ext_vector_type(4))) __bf16 bf16x4;
typedef __attribute__((ext_vector_type(8))) __bf16 bf16x8;
typedef __attribute__((ext_vector_type(16))) float f32x16;
typedef __attribute__((ext_vector_type(4)))  float f32x4;

#define N_NODES 16384
#define MFMA3(ACC, A, B) \
    ACC = __builtin_amdgcn_mfma_f32_32x32x16_bf16(A, B, ACC, 0, 0, 0)

// Fragment layout for the B operand of mfma_f32_32x32x16_bf16:
// element (k=r, col=c) -> 1KiB units indexed by (K16 = r>>4, cblk = c>>5),
// within a unit: lane = (c&31) + 32*((r>>3)&1) holds 8 bf16 (k = ..8g..8g+7).
__device__ __forceinline__ int frag_off(int r, int c) {
    int K16  = r >> 4;
    int cblk = c >> 5;
    int g    = (r >> 3) & 1;
    int lane = (c & 31) + (g << 5);
    return ((K16 * 4 + cblk) << 9) + (lane << 3) + (r & 7);
}

__device__ __forceinline__ float4 relu_add4(float4 a, float4 b) {
    float4 r;
    r.x = fmaxf(a.x + b.x, 0.f); r.y = fmaxf(a.y + b.y, 0.f);
    r.z = fmaxf(a.z + b.z, 0.f); r.w = fmaxf(a.w + b.w, 0.f);
    return r;
}

// ---------------------------------------------------------------------------
// Small fp32 GEMM producer: out = A[16384][K] @ W[K][128]; epilogue splits
// each output into bf16 hi/lo and scatters into the fragment layout.
// ADD2: A := relu(A + A2) elementwise (fused partial-reduce of the hidden).
// ---------------------------------------------------------------------------
template<int K, bool FUSED, bool ADD2>
__global__ __launch_bounds__(256)
void producer_kernel(const float* __restrict__ A,
                     const float* __restrict__ A2,
                     const float* __restrict__ W,
                     const float* __restrict__ Wa,
                     const float* __restrict__ Wb,
                     bf16_t* __restrict__ Bh,
                     bf16_t* __restrict__ Bl)
{
    __shared__ float As[32][128];   // k-major A tile: As[k][r]
    __shared__ float Wsh[32][128];  // Wsh[k][c]
    const int t    = threadIdx.x;
    const int row0 = blockIdx.x * 128;
    const int tc   = t & 15, tr = t >> 4;   // 16x16 thread grid, 8x8 outs each

    float acc[8][8];
    #pragma unroll
    for (int i = 0; i < 8; ++i)
        #pragma unroll
        for (int j = 0; j < 8; ++j) acc[i][j] = 0.f;

    const int ra = t >> 1, ks = (t & 1) << 4;   // A staging: 16 f32/thread
    const int wk = t >> 3, wc = (t & 7) << 4;   // W staging: 16 f32/thread

    for (int k0 = 0; k0 < K; k0 += 32) {
        const float* ap = A + (size_t)(row0 + ra) * K + k0 + ks;
        float4 a0 = *(const float4*)(ap);
        float4 a1 = *(const float4*)(ap + 4);
        float4 a2 = *(const float4*)(ap + 8);
        float4 a3 = *(const float4*)(ap + 12);
        if (ADD2) {
            const float* ap2 = A2 + (size_t)(row0 + ra) * K + k0 + ks;
            a0 = relu_add4(a0, *(const float4*)(ap2));
            a1 = relu_add4(a1, *(const float4*)(ap2 + 4));
            a2 = relu_add4(a2, *(const float4*)(ap2 + 8));
            a3 = relu_add4(a3, *(const float4*)(ap2 + 12));
        }
        float4 w0, w1, w2, w3;
        if (!FUSED) {
            const float* wp = W + (size_t)(k0 + wk) * 128 + wc;
            w0 = *(const float4*)(wp);     w1 = *(const float4*)(wp + 4);
            w2 = *(const float4*)(wp + 8); w3 = *(const float4*)(wp + 12);
        } else {
            const float* wp = (wc < 64) ? (Wa + (size_t)(k0 + wk) * 64 + wc)
                                        : (Wb + (size_t)(k0 + wk) * 64 + (wc - 64));
            w0 = *(const float4*)(wp);     w1 = *(const float4*)(wp + 4);
            w2 = *(const float4*)(wp + 8); w3 = *(const float4*)(wp + 12);
        }
        __syncthreads();   // previous iteration's compute done before overwrite
        {
            float tmp[16] = {a0.x,a0.y,a0.z,a0.w, a1.x,a1.y,a1.z,a1.w,
                             a2.x,a2.y,a2.z,a2.w, a3.x,a3.y,a3.z,a3.w};
            #pragma unroll
            for (int j = 0; j < 16; ++j) As[ks + j][ra] = tmp[j];
            *(float4*)&Wsh[wk][wc     ] = w0;
            *(float4*)&Wsh[wk][wc +  4] = w1;
            *(float4*)&Wsh[wk][wc +  8] = w2;
            *(float4*)&Wsh[wk][wc + 12] = w3;
        }
        __syncthreads();
        #pragma unroll 4
        for (int k = 0; k < 32; ++k) {
            float av[8], wv[8];
            *(float4*)&av[0] = *(const float4*)&As[k][8 * tr];
            *(float4*)&av[4] = *(const float4*)&As[k][8 * tr + 4];
            *(float4*)&wv[0] = *(const float4*)&Wsh[k][8 * tc];
            *(float4*)&wv[4] = *(const float4*)&Wsh[k][8 * tc + 4];
            #pragma unroll
            for (int i = 0; i < 8; ++i)
                #pragma unroll
                for (int j = 0; j < 8; ++j)
                    acc[i][j] = fmaf(av[i], wv[j], acc[i][j]);
        }
    }

    #pragma unroll
    for (int i = 0; i < 8; ++i) {
        int r = row0 + 8 * tr + i;
        #pragma unroll
        for (int j = 0; j < 8; ++j) {
            int c = 8 * tc + j;
            float v = acc[i][j];
            bf16_t h = (bf16_t)v;
            bf16_t l = (bf16_t)(v - (float)h);
            int off = frag_off(r, c);
            Bh[off] = h;
            Bl[off] = l;
        }
    }
}

// ---------------------------------------------------------------------------
// Big kernel: P_kh = adj[rows, kh-half] @ B[kh-half], M-tile 32, K-half 8192.
// grid 1024 (512 mt x 2 kh) = 4 blocks/CU, 256 thr (4 waves = 4 B
// col-quadrants). 32 macros of K=256, processed in ROTATED order
// (m+ph)&31 so concurrent blocks read different k-windows (R15).
// Single-buffer LDS [32][256] hi+lo = 32KB. adj: wave w stages rows
// w*8..w*8+7, one 1KB dwordx4 burst per row. Two lgkm-only barriers per
// macro; latency hiding via the 3 other co-resident blocks.
// LDS swizzle: elem (r,k) at (r<<8) + (((k>>4) ^ (r&15))<<4) + (k&15).
// ---------------------------------------------------------------------------
struct BSet { bf16x8 h[4]; bf16x8 l[4]; };   // 32 VGPRs

__global__ __launch_bounds__(256, 4)
void adj_gemm_kernel(const float* __restrict__ adj,
                     const bf16_t* __restrict__ Bh,
                     const bf16_t* __restrict__ Bl,
                     float* __restrict__ P0,
                     float* __restrict__ P1)
{
    __shared__ __align__(16) bf16_t AsH[32 * 256];
    __shared__ __align__(16) bf16_t AsL[32 * 256];
    const int t    = threadIdx.x;
    const int lane = t & 63;
    const int w    = t >> 6;                 // wave = B col-quadrant
    const int bid  = blockIdx.x;
    const int mt   = bid >> 1;
    const int kh   = bid & 1;
    const int row0 = mt << 5;
    const int hi32 = lane >> 5;
    float* const outP = kh ? P1 : P0;

    // R15: per-block K-phase; macros processed in order (m+ph)&31.
    const int ph = (bid * 5 + (bid >> 3)) & 31;

    // adj staging: wave w stages rows w*8+j (j=0..7), one wave-wide dwordx4
    // burst per row (64 lanes x 16B = 1KB contiguous); macro k-span 256.
    const float* aBase = adj + (size_t)(row0 + (w << 3)) * 16384
                             + (kh << 13) + (lane << 2);

    // LDS write indices: row = w*8+j, elems k = lane*4..+3
    int wIdx[8];
    #pragma unroll
    for (int j = 0; j < 8; ++j) {
        int row = (w << 3) + j;
        wIdx[j] = (row << 8) + ((((lane >> 2) ^ (row & 15)) << 4)
                                + ((lane & 3) << 2));
    }

    // LDS read: row frow = lane&31, unit u = s*4+k16, elem-in-unit = hi32*8
    const int frow  = lane & 31;
    const int rbase = (frow << 8) + (hi32 << 3);
    const int rx    = frow & 15;

    // B frag per-thread base; sub (K=64) stride = 8192 elems
    const int tb   = (w << 9) + (lane << 3);
    const int sub0 = kh << 7;                // kh*128 subs

    f32x16 acc;
    #pragma unroll
    for (int i = 0; i < 16; ++i) acc[i] = 0.f;

    f32x4 ar[8];
    BSet S;

    auto loadAdj = [&](int mac) {
        const float* p = aBase + (mac << 8);
        #pragma unroll
        for (int j = 0; j < 8; ++j)
            ar[j] = __builtin_nontemporal_load((const f32x4*)(p + (size_t)j * 16384));
    };
    auto cvtWrite = [&]() {
        #pragma unroll
        for (int j = 0; j < 8; ++j) {
            bf16x4 hv, lv;
            #pragma unroll
            for (int e = 0; e < 4; ++e) {
                float v = ar[j][e];
                bf16_t h = (bf16_t)v;
                hv[e] = h;
                lv[e] = (bf16_t)(v - (float)h);
            }
            *(bf16x4*)&AsH[wIdx[j]] = hv;
            *(bf16x4*)&AsL[wIdx[j]] = lv;
        }
    };
    auto loadB = [&](int sub) {
        const size_t base = ((size_t)sub << 13) + tb;
        #pragma unroll
        for (int s = 0; s < 4; ++s) {
            S.h[s] = *(const bf16x8*)(Bh + base + (s << 11));
            S.l[s] = *(const bf16x8*)(Bl + base + (s << 11));
        }
    };
    auto computeS = [&](int s) {
        #pragma unroll
        for (int k16 = 0; k16 < 4; ++k16) {
            const int u  = (s << 2) + k16;
            const int id = rbase + ((u ^ rx) << 4);
            bf16x8 ah = *(const bf16x8*)&AsH[id];
            bf16x8 al = *(const bf16x8*)&AsL[id];
            MFMA3(acc, ah, S.h[k16]);
            MFMA3(acc, ah, S.l[k16]);
            MFMA3(acc, al, S.h[k16]);
        }
    };

    // lgkm-only barrier: ds ops drained; register-dest global loads stay in
    // flight across the barrier (counted vmcnt by compiler).
#define SYNC_LDS() do { asm volatile("s_waitcnt lgkmcnt(0)" ::: "memory"); \
                        __builtin_amdgcn_s_barrier(); } while (0)

    int mm = ph;                             // physical macro index (rotated)
    loadAdj(mm);
    for (int m = 0; m < 32; ++m) {
        cvtWrite();                          // waits ar = adj(mm)
        SYNC_LDS();                          // staged tile visible
        const int sb = sub0 + (mm << 2);
        loadB(sb + 0);
        const int mn = (mm + 1) & 31;
        if (m < 31) loadAdj(mn);             // in flight across the macro
        computeS(0);
        loadB(sb + 1);  computeS(1);
        loadB(sb + 2);  computeS(2);
        loadB(sb + 3);  computeS(3);
        SYNC_LDS();                          // reads done before overwrite
        mm = mn;
    }
#undef SYNC_LDS

    // C write: col = w*32 + lane&31, row = (q&3) + 8*(q>>2) + 4*hi32
    const int col = (w << 5) + (lane & 31);
    const int rb  = row0 + (hi32 << 2);
    #pragma unroll
    for (int q = 0; q < 16; ++q) {
        int r = rb + (q & 3) + ((q >> 2) << 3);
        outP[(size_t)r * 128 + col] = acc[q];
    }
}

// ---------------------------------------------------------------------------
// Final: T = T0+T1 ([16384][128], Z cols 0-63 | logstd cols 64-127);
// mean = Z@Wp + bp; out = noise*exp(min(logstd,10)) + mean
// ---------------------------------------------------------------------------
__global__ __launch_bounds__(256)
void final_kernel(const float* __restrict__ T0,
                  const float* __restrict__ T1,
                  const float* __restrict__ Wp,
                  const float* __restrict__ bp,
                  const float* __restrict__ noise,
                  float* __restrict__ out)
{
    __shared__ float Wps[64][64];
    __shared__ float Ts[64][64];
    const int t = threadIdx.x;
    const int row0 = blockIdx.x * 64;
    {
        int k = t >> 2, c0 = (t & 3) << 4;
        #pragma unroll
        for (int i = 0; i < 4; ++i)
            *(float4*)&Wps[k][c0 + 4 * i] = *(const float4*)&Wp[(size_t)k * 64 + c0 + 4 * i];
        #pragma unroll
        for (int i = 0; i < 4; ++i) {
            float4 z0 = *(const float4*)&T0[(size_t)(row0 + k) * 128 + c0 + 4 * i];
            float4 z1 = *(const float4*)&T1[(size_t)(row0 + k) * 128 + c0 + 4 * i];
            float4 zs; zs.x = z0.x + z1.x; zs.y = z0.y + z1.y;
            zs.z = z0.z + z1.z; zs.w = z0.w + z1.w;
            *(float4*)&Ts[k][c0 + 4 * i] = zs;
        }
    }
    __syncthreads();

    const int r  = t >> 2;
    const int c0 = (t & 3) << 4;
    float acc[16];
    #pragma unroll
    for (int j = 0; j < 16; ++j) acc[j] = bp[c0 + j];
    for (int k = 0; k < 64; ++k) {
        float a = Ts[r][k];
        #pragma unroll
        for (int j = 0; j < 16; ++j) acc[j] = fmaf(a, Wps[k][c0 + j], acc[j]);
    }
    const int grow = row0 + r;
    #pragma unroll
    for (int j = 0; j < 16; ++j) {
        size_t li = (size_t)grow * 128 + 64 + c0 + j;
        float ls = T0[li] + T1[li];
        ls = fminf(ls, 10.0f);
        out[(size_t)grow * 64 + c0 + j] =
            noise[(size_t)grow * 64 + c0 + j] * __expf(ls) + acc[j];
    }
}

// ---------------------------------------------------------------------------
extern "C" void kernel_launch(void* const* d_in, const int* in_sizes, int n_in,
                              void* d_out, int out_size, void* d_ws, size_t ws_size,
                              hipStream_t stream) {
    const float* X     = (const float*)d_in[0];
    const float* adj   = (const float*)d_in[1];
    const float* W1    = (const float*)d_in[2];
    const float* Wm    = (const float*)d_in[3];
    const float* Wsv   = (const float*)d_in[4];
    const float* Wp    = (const float*)d_in[5];
    const float* bp    = (const float*)d_in[6];
    const float* noise = (const float*)d_in[7];
    float* out = (float*)d_out;

    char* ws = (char*)d_ws;
    bf16_t* Bh = (bf16_t*)ws;                     // 4 MB
    bf16_t* Bl = (bf16_t*)(ws + (4u << 20));      // 4 MB
    float*  P0 = (float*)(ws + (8u << 20));       // 8 MB partial (kh=0)
    float*  P1 = (float*)(ws + (16u << 20));      // 8 MB partial (kh=1)

    // S1: B1 = fragsplit((X @ W1)^T)
    producer_kernel<256, false, false><<<128, 256, 0, stream>>>(
        X, nullptr, W1, nullptr, nullptr, Bh, Bl);
    // S2: hidden partials: P_kh = adj[:, kh-half] @ B1[kh-half]
    adj_gemm_kernel<<<1024, 256, 0, stream>>>(adj, Bh, Bl, P0, P1);
    // S3: B2 = fragsplit((relu(P0+P1) @ [Wm|Ws])^T)   (reduce+relu fused)
    producer_kernel<128, true, true><<<128, 256, 0, stream>>>(
        P0, P1, nullptr, Wm, Wsv, Bh, Bl);
    // S4: T partials
    adj_gemm_kernel<<<1024, 256, 0, stream>>>(adj, Bh, Bl, P0, P1);
    // S5: epilogue (T = P0+P1 summed on the fly)
    final_kernel<<<256, 256, 0, stream>>>(P0, P1, Wp, bp, noise, out);
}